// Round 3
// baseline (2595.814 us; speedup 1.0000x reference)
//
#include <hip/hip_runtime.h>
#include <math.h>

// ---------------------------------------------------------------------------
// PseqStepV3: 3-layer TransformerConv (heads=1), N=50000, E=800000, D=64.
//   setup: detect edge dtype, build CSR by dst (multi-block scan)
//   per layer: fused q/k/v/s GEMM (readlane broadcast, no bpermute)
//              -> fused online-softmax aggregation (k,v gathers only)
// ---------------------------------------------------------------------------

#define D64 64

// ---- edge_index format detection: int64 rows have zero high words ----------
__global__ void detect_fmt(const int* __restrict__ ei, int nchecks, int* flag) {
    int t = blockIdx.x * blockDim.x + threadIdx.x;
    int acc = 0;
    for (int i = t; i < nchecks; i += blockDim.x * gridDim.x)
        acc |= ei[2 * i + 1];
    if (acc) atomicOr(flag, 1);   // nonzero => plain int32 layout
}

__device__ __forceinline__ int load_src(const int* ei, int e, int E, int is64) {
    return is64 ? ei[2 * e] : ei[e];
}
__device__ __forceinline__ int load_dst(const int* ei, int e, int E, int is64) {
    return is64 ? ei[2 * E + 2 * e] : ei[E + e];
}

// ---- CSR build -------------------------------------------------------------
__global__ void hist_dst(const int* __restrict__ ei, int* __restrict__ counts,
                         int E, const int* __restrict__ flag) {
    int e = blockIdx.x * blockDim.x + threadIdx.x;
    if (e >= E) return;
    int is64 = (*flag == 0);
    atomicAdd(&counts[load_dst(ei, e, E, is64)], 1);
}

__global__ void scan_blocks(const int* __restrict__ counts, int* __restrict__ partial,
                            int* __restrict__ blockSums, int n) {
    int tid = threadIdx.x;                 // 256
    int base = blockIdx.x * 1024 + tid * 4;
    int4 c = make_int4(0, 0, 0, 0);
    if (base + 3 < n) c = *(const int4*)&counts[base];
    else {
        if (base + 0 < n) c.x = counts[base + 0];
        if (base + 1 < n) c.y = counts[base + 1];
        if (base + 2 < n) c.z = counts[base + 2];
        if (base + 3 < n) c.w = counts[base + 3];
    }
    int s1 = c.x, s2 = s1 + c.y, s3 = s2 + c.z, s4 = s3 + c.w;
    int lane = tid & 63, wave = tid >> 6;
    int v = s4;
#pragma unroll
    for (int off = 1; off < 64; off <<= 1) {
        int t = __shfl_up(v, off);
        if (lane >= off) v += t;
    }
    __shared__ int wsum[4];
    if (lane == 63) wsum[wave] = v;
    __syncthreads();
    int wpre = 0;
    for (int w = 0; w < wave; ++w) wpre += wsum[w];
    int pre = wpre + v - s4;
    if (base + 0 < n) partial[base + 0] = pre + s1;
    if (base + 1 < n) partial[base + 1] = pre + s2;
    if (base + 2 < n) partial[base + 2] = pre + s3;
    if (base + 3 < n) partial[base + 3] = pre + s4;
    if (tid == 255) blockSums[blockIdx.x] = wsum[0] + wsum[1] + wsum[2] + wsum[3];
}

__global__ void scan_sums(int* __restrict__ bs, int nb) {
    int lane = threadIdx.x;                // 64
    int carry = 0;
    for (int b0 = 0; b0 < nb; b0 += 64) {
        int i = b0 + lane;
        int val = (i < nb) ? bs[i] : 0;
        int v = val;
#pragma unroll
        for (int off = 1; off < 64; off <<= 1) {
            int t = __shfl_up(v, off);
            if (lane >= off) v += t;
        }
        if (i < nb) bs[i] = carry + v - val;   // exclusive
        carry += __shfl(v, 63);
    }
}

__global__ void scan_final(const int* __restrict__ counts, const int* __restrict__ partial,
                           const int* __restrict__ bs, int* __restrict__ offsets,
                           int* __restrict__ nxt, int n) {
    int i = blockIdx.x * 256 + threadIdx.x;
    if (i >= n) return;
    int inc = partial[i] + bs[i >> 10];
    offsets[i + 1] = inc;
    nxt[i] = inc - counts[i];
    if (i == 0) offsets[0] = 0;
}

__global__ void scatter_csr(const int* __restrict__ ei, int* __restrict__ nxt,
                            int* __restrict__ csr_src, int E,
                            const int* __restrict__ flag) {
    int e = blockIdx.x * blockDim.x + threadIdx.x;
    if (e >= E) return;
    int is64 = (*flag == 0);
    int s = load_src(ei, e, E, is64);
    int d = load_dst(ei, e, E, is64);
    int pos = atomicAdd(&nxt[d], 1);
    csr_src[pos] = s;
}

// ---- fused q/k/v/s GEMM ----------------------------------------------------
// Wave handles 8 rows x 4 matrices. Broadcast of x[r][c] via readlane (SGPR),
// weights quad (q,k,v,s channel d of input c) via one ds_read_b128 per c-step:
// 1 LDS op per 32 FMAs, zero bpermute.
__launch_bounds__(256, 2)
__global__ void gemm_qkvs(const float* __restrict__ x,
                          const float* __restrict__ Wq, const float* __restrict__ bq,
                          const float* __restrict__ Wk, const float* __restrict__ bk,
                          const float* __restrict__ Wv, const float* __restrict__ bv,
                          const float* __restrict__ Ws, const float* __restrict__ bs,
                          float* __restrict__ q, float* __restrict__ k,
                          float* __restrict__ v, float* __restrict__ s, int n) {
    __shared__ float W4[64 * 256];  // 64 KiB: W4[c][lane][4] interleaved
    int tid = threadIdx.x;
    for (int i = tid; i < 64 * 64; i += 256) {
        int c = i >> 6, l = i & 63;
        float* p = &W4[c * 256 + l * 4];
        p[0] = Wq[i]; p[1] = Wk[i]; p[2] = Wv[i]; p[3] = Ws[i];
    }
    __syncthreads();

    int wave = tid >> 6, lane = tid & 63;
    int row0 = blockIdx.x * 32 + wave * 8;

    float xr[8];
#pragma unroll
    for (int j = 0; j < 8; ++j)
        xr[j] = (row0 + j < n) ? x[(size_t)(row0 + j) * D64 + lane] : 0.f;

    float bqv = bq[lane], bkv = bk[lane], bvv = bv[lane], bsv = bs[lane];
    float aq[8], ak[8], av[8], as_[8];
#pragma unroll
    for (int j = 0; j < 8; ++j) { aq[j] = bqv; ak[j] = bkv; av[j] = bvv; as_[j] = bsv; }

#pragma unroll
    for (int c = 0; c < 64; ++c) {
        const float4 w = *(const float4*)&W4[c * 256 + lane * 4];
#pragma unroll
        for (int j = 0; j < 8; ++j) {
            float xs = __int_as_float(__builtin_amdgcn_readlane(__float_as_int(xr[j]), c));
            aq[j] += xs * w.x;
            ak[j] += xs * w.y;
            av[j] += xs * w.z;
            as_[j] += xs * w.w;
        }
    }
#pragma unroll
    for (int j = 0; j < 8; ++j) {
        if (row0 + j < n) {
            size_t o = (size_t)(row0 + j) * D64 + lane;
            q[o] = aq[j]; k[o] = ak[j]; v[o] = av[j]; s[o] = as_[j];
        }
    }
}

// ---- fused edge-score + online-softmax aggregation + epilogue --------------
// Wave = 1 node. 4 groups x 16 lanes; group owns one edge/iter, lane l16 owns
// channels [4*l16, 4*l16+4). Online (m, denom, acc) per group; merged via
// shfl_xor(16/32) at the end. q[node] stays in registers -> no q gather, no
// scores buffer, no separate edge kernel.
// MODE 1: out = silu(t)   MODE 2: out = silu(t + xin)   MODE 3: out = t + 0.1*z
template <int MODE>
__launch_bounds__(256)
__global__ void agg_fused(const float* __restrict__ q, const float* __restrict__ k,
                          const float* __restrict__ v, const int* __restrict__ csr_src,
                          const int* __restrict__ offsets,
                          const float* __restrict__ sbuf, const float* __restrict__ xin,
                          const float* __restrict__ z, float* __restrict__ out, int n) {
    int node = blockIdx.x * 4 + (threadIdx.x >> 6);
    if (node >= n) return;
    int lane = threadIdx.x & 63;
    int grp = lane >> 4, l16 = lane & 15;
    int start = offsets[node], end = offsets[node + 1];
    size_t co = (size_t)node * D64 + l16 * 4;
    float4 t = *(const float4*)(sbuf + co);   // skip term

    if (end > start) {
        const float4 q4 = *(const float4*)(q + co);
        float m = -3.0e38f, den = 0.f;
        float4 acc = make_float4(0.f, 0.f, 0.f, 0.f);

        int i = start + grp;
        int sj = (i < end) ? csr_src[i] : 0;
        while (i < end) {
            int inext = i + 4;
            int sjn = (inext < end) ? csr_src[inext] : 0;   // prefetch next index
            const float4 k4 = *(const float4*)(k + (size_t)sj * D64 + l16 * 4);
            const float4 v4 = *(const float4*)(v + (size_t)sj * D64 + l16 * 4);
            float p = q4.x * k4.x + q4.y * k4.y + q4.z * k4.z + q4.w * k4.w;
            p += __shfl_xor(p, 1, 16);
            p += __shfl_xor(p, 2, 16);
            p += __shfl_xor(p, 4, 16);
            p += __shfl_xor(p, 8, 16);
            p *= 0.125f;                       // 1/sqrt(64)
            float nm = fmaxf(m, p);
            float f  = __expf(m - nm);         // 1 when m unchanged
            float e  = __expf(p - nm);
            den = den * f + e;
            acc.x = acc.x * f + e * v4.x;
            acc.y = acc.y * f + e * v4.y;
            acc.z = acc.z * f + e * v4.z;
            acc.w = acc.w * f + e * v4.w;
            m = nm;
            sj = sjn; i = inext;
        }
        // merge the 4 groups (empty groups: m=-3e38 -> factor exp()->0)
        float M = fmaxf(m, __shfl_xor(m, 16));
        M = fmaxf(M, __shfl_xor(M, 32));
        float f = __expf(m - M);
        float dd = den * f;
        dd += __shfl_xor(dd, 16);
        dd += __shfl_xor(dd, 32);
        acc.x *= f; acc.y *= f; acc.z *= f; acc.w *= f;
        acc.x += __shfl_xor(acc.x, 16); acc.x += __shfl_xor(acc.x, 32);
        acc.y += __shfl_xor(acc.y, 16); acc.y += __shfl_xor(acc.y, 32);
        acc.z += __shfl_xor(acc.z, 16); acc.z += __shfl_xor(acc.z, 32);
        acc.w += __shfl_xor(acc.w, 16); acc.w += __shfl_xor(acc.w, 32);
        float inv = 1.f / dd;
        t.x += acc.x * inv; t.y += acc.y * inv;
        t.z += acc.z * inv; t.w += acc.w * inv;
    }
    if (MODE == 1) {
        t.x = t.x / (1.f + __expf(-t.x));
        t.y = t.y / (1.f + __expf(-t.y));
        t.z = t.z / (1.f + __expf(-t.z));
        t.w = t.w / (1.f + __expf(-t.w));
    } else if (MODE == 2) {
        const float4 xi = *(const float4*)(xin + co);
        float ux = t.x + xi.x, uy = t.y + xi.y, uz = t.z + xi.z, uw = t.w + xi.w;
        t.x = ux / (1.f + __expf(-ux));
        t.y = uy / (1.f + __expf(-uy));
        t.z = uz / (1.f + __expf(-uz));
        t.w = uw / (1.f + __expf(-uw));
    } else {
        const float4 zi = *(const float4*)(z + co);
        t.x += 0.1f * zi.x; t.y += 0.1f * zi.y;
        t.z += 0.1f * zi.z; t.w += 0.1f * zi.w;
    }
    if (grp == 0) *(float4*)(out + co) = t;
}

// ---------------------------------------------------------------------------
extern "C" void kernel_launch(void* const* d_in, const int* in_sizes, int n_in,
                              void* d_out, int out_size, void* d_ws, size_t ws_size,
                              hipStream_t stream) {
    const float* x = (const float*)d_in[0];
    const int* ei  = (const int*)d_in[1];
    const float* z = (const float*)d_in[2];
    const float* W[3][4];
    const float* B[3][4];
    for (int l = 0; l < 3; ++l)
        for (int m = 0; m < 4; ++m) {
            W[l][m] = (const float*)d_in[3 + l * 8 + m * 2];
            B[l][m] = (const float*)d_in[3 + l * 8 + m * 2 + 1];
        }
    int N = in_sizes[0] / D64;
    int E = in_sizes[1] / 2;
    size_t ND = (size_t)N * D64;

    char* p = (char*)d_ws;
    auto alloc = [&](size_t bytes) {
        char* r = p;
        p += (bytes + 255) & ~(size_t)255;
        return r;
    };
    float* q       = (float*)alloc(ND * 4);
    float* k       = (float*)alloc(ND * 4);
    float* v       = (float*)alloc(ND * 4);
    float* sb      = (float*)alloc(ND * 4);
    float* hA      = (float*)alloc(ND * 4);
    int* csr_src   = (int*)alloc((size_t)E * 4);
    int* offsets   = (int*)alloc((size_t)(N + 1) * 4);
    int* counts    = (int*)alloc((size_t)N * 4);
    int* nxt       = (int*)alloc((size_t)N * 4);
    int* partial   = (int*)alloc((size_t)N * 4);
    int* blockSums = (int*)alloc(4096);
    int* flag      = (int*)alloc(4);
    float* outp    = (float*)d_out;

    hipMemsetAsync(flag, 0, 4, stream);
    hipMemsetAsync(counts, 0, (size_t)N * 4, stream);
    int nchecks = E < 4096 ? E : 4096;
    detect_fmt<<<1, 256, 0, stream>>>(ei, nchecks, flag);
    hist_dst<<<(E + 255) / 256, 256, 0, stream>>>(ei, counts, E, flag);
    int nb = (N + 1023) / 1024;
    scan_blocks<<<nb, 256, 0, stream>>>(counts, partial, blockSums, N);
    scan_sums<<<1, 64, 0, stream>>>(blockSums, nb);
    scan_final<<<(N + 255) / 256, 256, 0, stream>>>(counts, partial, blockSums,
                                                    offsets, nxt, N);
    scatter_csr<<<(E + 255) / 256, 256, 0, stream>>>(ei, nxt, csr_src, E, flag);

    int gemm_grid = (N + 31) / 32;
    int node_grid = (N + 3) / 4;

    // layer 1: x -> hA, silu
    gemm_qkvs<<<gemm_grid, 256, 0, stream>>>(x, W[0][0], B[0][0], W[0][1], B[0][1],
                                             W[0][2], B[0][2], W[0][3], B[0][3],
                                             q, k, v, sb, N);
    agg_fused<1><<<node_grid, 256, 0, stream>>>(q, k, v, csr_src, offsets, sb,
                                                nullptr, nullptr, hA, N);
    // layer 2: hA -> hA (residual + silu)
    gemm_qkvs<<<gemm_grid, 256, 0, stream>>>(hA, W[1][0], B[1][0], W[1][1], B[1][1],
                                             W[1][2], B[1][2], W[1][3], B[1][3],
                                             q, k, v, sb, N);
    agg_fused<2><<<node_grid, 256, 0, stream>>>(q, k, v, csr_src, offsets, sb,
                                                hA, nullptr, hA, N);
    // layer 3: hA -> out, + 0.1*z
    gemm_qkvs<<<gemm_grid, 256, 0, stream>>>(hA, W[2][0], B[2][0], W[2][1], B[2][1],
                                             W[2][2], B[2][2], W[2][3], B[2][3],
                                             q, k, v, sb, N);
    agg_fused<3><<<node_grid, 256, 0, stream>>>(q, k, v, csr_src, offsets, sb,
                                                nullptr, z, outp, N);
}

// Round 4
// 407.049 us; speedup vs baseline: 6.3772x; 6.3772x over previous
//
#include <hip/hip_runtime.h>
#include <math.h>

// ---------------------------------------------------------------------------
// PseqStepV3: 3-layer TransformerConv (heads=1), N=50000, E=800000, D=64.
//   setup: detect edge dtype, build CSR by dst (multi-block scan)
//   per layer: fused q/k/v/s GEMM (readlane broadcast, partial unroll,
//              no VGPR cap -> no scratch spill)
//              -> fused online-softmax aggregation (k,v gathers only)
// ---------------------------------------------------------------------------

#define D64 64

// ---- edge_index format detection: int64 rows have zero high words ----------
__global__ void detect_fmt(const int* __restrict__ ei, int nchecks, int* flag) {
    int t = blockIdx.x * blockDim.x + threadIdx.x;
    int acc = 0;
    for (int i = t; i < nchecks; i += blockDim.x * gridDim.x)
        acc |= ei[2 * i + 1];
    if (acc) atomicOr(flag, 1);   // nonzero => plain int32 layout
}

__device__ __forceinline__ int load_src(const int* ei, int e, int E, int is64) {
    return is64 ? ei[2 * e] : ei[e];
}
__device__ __forceinline__ int load_dst(const int* ei, int e, int E, int is64) {
    return is64 ? ei[2 * E + 2 * e] : ei[E + e];
}

// ---- CSR build -------------------------------------------------------------
__global__ void hist_dst(const int* __restrict__ ei, int* __restrict__ counts,
                         int E, const int* __restrict__ flag) {
    int e = blockIdx.x * blockDim.x + threadIdx.x;
    if (e >= E) return;
    int is64 = (*flag == 0);
    atomicAdd(&counts[load_dst(ei, e, E, is64)], 1);
}

__global__ void scan_blocks(const int* __restrict__ counts, int* __restrict__ partial,
                            int* __restrict__ blockSums, int n) {
    int tid = threadIdx.x;                 // 256
    int base = blockIdx.x * 1024 + tid * 4;
    int4 c = make_int4(0, 0, 0, 0);
    if (base + 3 < n) c = *(const int4*)&counts[base];
    else {
        if (base + 0 < n) c.x = counts[base + 0];
        if (base + 1 < n) c.y = counts[base + 1];
        if (base + 2 < n) c.z = counts[base + 2];
        if (base + 3 < n) c.w = counts[base + 3];
    }
    int s1 = c.x, s2 = s1 + c.y, s3 = s2 + c.z, s4 = s3 + c.w;
    int lane = tid & 63, wave = tid >> 6;
    int v = s4;
#pragma unroll
    for (int off = 1; off < 64; off <<= 1) {
        int t = __shfl_up(v, off);
        if (lane >= off) v += t;
    }
    __shared__ int wsum[4];
    if (lane == 63) wsum[wave] = v;
    __syncthreads();
    int wpre = 0;
    for (int w = 0; w < wave; ++w) wpre += wsum[w];
    int pre = wpre + v - s4;
    if (base + 0 < n) partial[base + 0] = pre + s1;
    if (base + 1 < n) partial[base + 1] = pre + s2;
    if (base + 2 < n) partial[base + 2] = pre + s3;
    if (base + 3 < n) partial[base + 3] = pre + s4;
    if (tid == 255) blockSums[blockIdx.x] = wsum[0] + wsum[1] + wsum[2] + wsum[3];
}

__global__ void scan_sums(int* __restrict__ bs, int nb) {
    int lane = threadIdx.x;                // 64
    int carry = 0;
    for (int b0 = 0; b0 < nb; b0 += 64) {
        int i = b0 + lane;
        int val = (i < nb) ? bs[i] : 0;
        int v = val;
#pragma unroll
        for (int off = 1; off < 64; off <<= 1) {
            int t = __shfl_up(v, off);
            if (lane >= off) v += t;
        }
        if (i < nb) bs[i] = carry + v - val;   // exclusive
        carry += __shfl(v, 63);
    }
}

__global__ void scan_final(const int* __restrict__ counts, const int* __restrict__ partial,
                           const int* __restrict__ bs, int* __restrict__ offsets,
                           int* __restrict__ nxt, int n) {
    int i = blockIdx.x * 256 + threadIdx.x;
    if (i >= n) return;
    int inc = partial[i] + bs[i >> 10];
    offsets[i + 1] = inc;
    nxt[i] = inc - counts[i];
    if (i == 0) offsets[0] = 0;
}

__global__ void scatter_csr(const int* __restrict__ ei, int* __restrict__ nxt,
                            int* __restrict__ csr_src, int E,
                            const int* __restrict__ flag) {
    int e = blockIdx.x * blockDim.x + threadIdx.x;
    if (e >= E) return;
    int is64 = (*flag == 0);
    int s = load_src(ei, e, E, is64);
    int d = load_dst(ei, e, E, is64);
    int pos = atomicAdd(&nxt[d], 1);
    csr_src[pos] = s;
}

// ---- fused q/k/v/s GEMM ----------------------------------------------------
// Wave handles 8 rows x 4 matrices. Broadcast of x[r][c] via readlane (SGPR
// path, zero LDS traffic); weight quad (q,k,v,s channel `lane` of input c)
// via one ds_read_b128 per c-step: 1 LDS op per 32 FMAs.
// NOTE: partial unroll (4) + uncapped VGPR budget -- the R3 full unroll under
// __launch_bounds__(256,2) hoisted up to 64 weight quads, blew the 128-VGPR
// cap, and spilled accumulators to scratch (1.6 GB/dispatch of HBM traffic).
__launch_bounds__(256)
__global__ void gemm_qkvs(const float* __restrict__ x,
                          const float* __restrict__ Wq, const float* __restrict__ bq,
                          const float* __restrict__ Wk, const float* __restrict__ bk,
                          const float* __restrict__ Wv, const float* __restrict__ bv,
                          const float* __restrict__ Ws, const float* __restrict__ bs,
                          float* __restrict__ q, float* __restrict__ k,
                          float* __restrict__ v, float* __restrict__ s, int n) {
    __shared__ float W4[64 * 256];  // 64 KiB: W4[c][lane][4] interleaved
    int tid = threadIdx.x;
    for (int i = tid; i < 64 * 64; i += 256) {
        int c = i >> 6, l = i & 63;
        float4 wv4;
        wv4.x = Wq[i]; wv4.y = Wk[i]; wv4.z = Wv[i]; wv4.w = Ws[i];
        *(float4*)&W4[c * 256 + l * 4] = wv4;
    }
    __syncthreads();

    int wave = tid >> 6, lane = tid & 63;
    int row0 = blockIdx.x * 32 + wave * 8;

    float xr[8];
#pragma unroll
    for (int j = 0; j < 8; ++j)
        xr[j] = (row0 + j < n) ? x[(size_t)(row0 + j) * D64 + lane] : 0.f;

    float bqv = bq[lane], bkv = bk[lane], bvv = bv[lane], bsv = bs[lane];
    float aq[8], ak[8], av[8], as_[8];
#pragma unroll
    for (int j = 0; j < 8; ++j) { aq[j] = bqv; ak[j] = bkv; av[j] = bvv; as_[j] = bsv; }

#pragma unroll 4
    for (int c = 0; c < 64; ++c) {
        const float4 w = *(const float4*)&W4[c * 256 + lane * 4];
#pragma unroll
        for (int j = 0; j < 8; ++j) {
            float xs = __int_as_float(__builtin_amdgcn_readlane(__float_as_int(xr[j]), c));
            aq[j] += xs * w.x;
            ak[j] += xs * w.y;
            av[j] += xs * w.z;
            as_[j] += xs * w.w;
        }
    }
#pragma unroll
    for (int j = 0; j < 8; ++j) {
        if (row0 + j < n) {
            size_t o = (size_t)(row0 + j) * D64 + lane;
            q[o] = aq[j]; k[o] = ak[j]; v[o] = av[j]; s[o] = as_[j];
        }
    }
}

// ---- fused edge-score + online-softmax aggregation + epilogue --------------
// Wave = 1 node. 4 groups x 16 lanes; group owns one edge/iter, lane l16 owns
// channels [4*l16, 4*l16+4). Online (m, denom, acc) per group; merged via
// shfl_xor(16/32) at the end. q[node] stays in registers.
// MODE 1: out = silu(t)   MODE 2: out = silu(t + xin)   MODE 3: out = t + 0.1*z
template <int MODE>
__launch_bounds__(256)
__global__ void agg_fused(const float* __restrict__ q, const float* __restrict__ k,
                          const float* __restrict__ v, const int* __restrict__ csr_src,
                          const int* __restrict__ offsets,
                          const float* __restrict__ sbuf, const float* __restrict__ xin,
                          const float* __restrict__ z, float* __restrict__ out, int n) {
    int node = blockIdx.x * 4 + (threadIdx.x >> 6);
    if (node >= n) return;
    int lane = threadIdx.x & 63;
    int grp = lane >> 4, l16 = lane & 15;
    int start = offsets[node], end = offsets[node + 1];
    size_t co = (size_t)node * D64 + l16 * 4;
    float4 t = *(const float4*)(sbuf + co);   // skip term

    if (end > start) {
        const float4 q4 = *(const float4*)(q + co);
        float m = -3.0e38f, den = 0.f;
        float4 acc = make_float4(0.f, 0.f, 0.f, 0.f);

        int i = start + grp;
        int sj = (i < end) ? csr_src[i] : 0;
        while (i < end) {
            int inext = i + 4;
            int sjn = (inext < end) ? csr_src[inext] : 0;   // prefetch next index
            const float4 k4 = *(const float4*)(k + (size_t)sj * D64 + l16 * 4);
            const float4 v4 = *(const float4*)(v + (size_t)sj * D64 + l16 * 4);
            float p = q4.x * k4.x + q4.y * k4.y + q4.z * k4.z + q4.w * k4.w;
            p += __shfl_xor(p, 1, 16);
            p += __shfl_xor(p, 2, 16);
            p += __shfl_xor(p, 4, 16);
            p += __shfl_xor(p, 8, 16);
            p *= 0.125f;                       // 1/sqrt(64)
            float nm = fmaxf(m, p);
            float f  = __expf(m - nm);         // 1 when m unchanged
            float e  = __expf(p - nm);
            den = den * f + e;
            acc.x = acc.x * f + e * v4.x;
            acc.y = acc.y * f + e * v4.y;
            acc.z = acc.z * f + e * v4.z;
            acc.w = acc.w * f + e * v4.w;
            m = nm;
            sj = sjn; i = inext;
        }
        // merge the 4 groups (empty groups: m=-3e38 -> factor exp()->0)
        float M = fmaxf(m, __shfl_xor(m, 16));
        M = fmaxf(M, __shfl_xor(M, 32));
        float f = __expf(m - M);
        float dd = den * f;
        dd += __shfl_xor(dd, 16);
        dd += __shfl_xor(dd, 32);
        acc.x *= f; acc.y *= f; acc.z *= f; acc.w *= f;
        acc.x += __shfl_xor(acc.x, 16); acc.x += __shfl_xor(acc.x, 32);
        acc.y += __shfl_xor(acc.y, 16); acc.y += __shfl_xor(acc.y, 32);
        acc.z += __shfl_xor(acc.z, 16); acc.z += __shfl_xor(acc.z, 32);
        acc.w += __shfl_xor(acc.w, 16); acc.w += __shfl_xor(acc.w, 32);
        float inv = 1.f / dd;
        t.x += acc.x * inv; t.y += acc.y * inv;
        t.z += acc.z * inv; t.w += acc.w * inv;
    }
    if (MODE == 1) {
        t.x = t.x / (1.f + __expf(-t.x));
        t.y = t.y / (1.f + __expf(-t.y));
        t.z = t.z / (1.f + __expf(-t.z));
        t.w = t.w / (1.f + __expf(-t.w));
    } else if (MODE == 2) {
        const float4 xi = *(const float4*)(xin + co);
        float ux = t.x + xi.x, uy = t.y + xi.y, uz = t.z + xi.z, uw = t.w + xi.w;
        t.x = ux / (1.f + __expf(-ux));
        t.y = uy / (1.f + __expf(-uy));
        t.z = uz / (1.f + __expf(-uz));
        t.w = uw / (1.f + __expf(-uw));
    } else {
        const float4 zi = *(const float4*)(z + co);
        t.x += 0.1f * zi.x; t.y += 0.1f * zi.y;
        t.z += 0.1f * zi.z; t.w += 0.1f * zi.w;
    }
    if (grp == 0) *(float4*)(out + co) = t;
}

// ---------------------------------------------------------------------------
extern "C" void kernel_launch(void* const* d_in, const int* in_sizes, int n_in,
                              void* d_out, int out_size, void* d_ws, size_t ws_size,
                              hipStream_t stream) {
    const float* x = (const float*)d_in[0];
    const int* ei  = (const int*)d_in[1];
    const float* z = (const float*)d_in[2];
    const float* W[3][4];
    const float* B[3][4];
    for (int l = 0; l < 3; ++l)
        for (int m = 0; m < 4; ++m) {
            W[l][m] = (const float*)d_in[3 + l * 8 + m * 2];
            B[l][m] = (const float*)d_in[3 + l * 8 + m * 2 + 1];
        }
    int N = in_sizes[0] / D64;
    int E = in_sizes[1] / 2;
    size_t ND = (size_t)N * D64;

    char* p = (char*)d_ws;
    auto alloc = [&](size_t bytes) {
        char* r = p;
        p += (bytes + 255) & ~(size_t)255;
        return r;
    };
    float* q       = (float*)alloc(ND * 4);
    float* k       = (float*)alloc(ND * 4);
    float* v       = (float*)alloc(ND * 4);
    float* sb      = (float*)alloc(ND * 4);
    float* hA      = (float*)alloc(ND * 4);
    int* csr_src   = (int*)alloc((size_t)E * 4);
    int* offsets   = (int*)alloc((size_t)(N + 1) * 4);
    int* counts    = (int*)alloc((size_t)N * 4);
    int* nxt       = (int*)alloc((size_t)N * 4);
    int* partial   = (int*)alloc((size_t)N * 4);
    int* blockSums = (int*)alloc(4096);
    int* flag      = (int*)alloc(4);
    float* outp    = (float*)d_out;

    hipMemsetAsync(flag, 0, 4, stream);
    hipMemsetAsync(counts, 0, (size_t)N * 4, stream);
    int nchecks = E < 4096 ? E : 4096;
    detect_fmt<<<1, 256, 0, stream>>>(ei, nchecks, flag);
    hist_dst<<<(E + 255) / 256, 256, 0, stream>>>(ei, counts, E, flag);
    int nb = (N + 1023) / 1024;
    scan_blocks<<<nb, 256, 0, stream>>>(counts, partial, blockSums, N);
    scan_sums<<<1, 64, 0, stream>>>(blockSums, nb);
    scan_final<<<(N + 255) / 256, 256, 0, stream>>>(counts, partial, blockSums,
                                                    offsets, nxt, N);
    scatter_csr<<<(E + 255) / 256, 256, 0, stream>>>(ei, nxt, csr_src, E, flag);

    int gemm_grid = (N + 31) / 32;
    int node_grid = (N + 3) / 4;

    // layer 1: x -> hA, silu
    gemm_qkvs<<<gemm_grid, 256, 0, stream>>>(x, W[0][0], B[0][0], W[0][1], B[0][1],
                                             W[0][2], B[0][2], W[0][3], B[0][3],
                                             q, k, v, sb, N);
    agg_fused<1><<<node_grid, 256, 0, stream>>>(q, k, v, csr_src, offsets, sb,
                                                nullptr, nullptr, hA, N);
    // layer 2: hA -> hA (residual + silu)
    gemm_qkvs<<<gemm_grid, 256, 0, stream>>>(hA, W[1][0], B[1][0], W[1][1], B[1][1],
                                             W[1][2], B[1][2], W[1][3], B[1][3],
                                             q, k, v, sb, N);
    agg_fused<2><<<node_grid, 256, 0, stream>>>(q, k, v, csr_src, offsets, sb,
                                                hA, nullptr, hA, N);
    // layer 3: hA -> out, + 0.1*z
    gemm_qkvs<<<gemm_grid, 256, 0, stream>>>(hA, W[2][0], B[2][0], W[2][1], B[2][1],
                                             W[2][2], B[2][2], W[2][3], B[2][3],
                                             q, k, v, sb, N);
    agg_fused<3><<<node_grid, 256, 0, stream>>>(q, k, v, csr_src, offsets, sb,
                                                nullptr, z, outp, N);
}

// Round 5
// 395.730 us; speedup vs baseline: 6.5595x; 1.0286x over previous
//
#include <hip/hip_runtime.h>
#include <math.h>

// ---------------------------------------------------------------------------
// PseqStepV3: 3-layer TransformerConv (heads=1), N=50000, E=800000, D=64.
//   setup: detect edge dtype, build CSR by dst (multi-block scan)
//   per layer: fused q/k/v/s GEMM (readlane broadcast, split-c 32KB LDS)
//              -> fused online-softmax aggregation
//                 (8 edge-groups x 8 lanes, 2-deep load pipeline)
// ---------------------------------------------------------------------------

#define D64 64

// ---- edge_index format detection: int64 rows have zero high words ----------
__global__ void detect_fmt(const int* __restrict__ ei, int nchecks, int* flag) {
    int t = blockIdx.x * blockDim.x + threadIdx.x;
    int acc = 0;
    for (int i = t; i < nchecks; i += blockDim.x * gridDim.x)
        acc |= ei[2 * i + 1];
    if (acc) atomicOr(flag, 1);   // nonzero => plain int32 layout
}

__device__ __forceinline__ int load_src(const int* ei, int e, int E, int is64) {
    return is64 ? ei[2 * e] : ei[e];
}
__device__ __forceinline__ int load_dst(const int* ei, int e, int E, int is64) {
    return is64 ? ei[2 * E + 2 * e] : ei[E + e];
}

// ---- CSR build -------------------------------------------------------------
__global__ void hist_dst(const int* __restrict__ ei, int* __restrict__ counts,
                         int E, const int* __restrict__ flag) {
    int e = blockIdx.x * blockDim.x + threadIdx.x;
    if (e >= E) return;
    int is64 = (*flag == 0);
    atomicAdd(&counts[load_dst(ei, e, E, is64)], 1);
}

__global__ void scan_blocks(const int* __restrict__ counts, int* __restrict__ partial,
                            int* __restrict__ blockSums, int n) {
    int tid = threadIdx.x;                 // 256
    int base = blockIdx.x * 1024 + tid * 4;
    int4 c = make_int4(0, 0, 0, 0);
    if (base + 3 < n) c = *(const int4*)&counts[base];
    else {
        if (base + 0 < n) c.x = counts[base + 0];
        if (base + 1 < n) c.y = counts[base + 1];
        if (base + 2 < n) c.z = counts[base + 2];
        if (base + 3 < n) c.w = counts[base + 3];
    }
    int s1 = c.x, s2 = s1 + c.y, s3 = s2 + c.z, s4 = s3 + c.w;
    int lane = tid & 63, wave = tid >> 6;
    int v = s4;
#pragma unroll
    for (int off = 1; off < 64; off <<= 1) {
        int t = __shfl_up(v, off);
        if (lane >= off) v += t;
    }
    __shared__ int wsum[4];
    if (lane == 63) wsum[wave] = v;
    __syncthreads();
    int wpre = 0;
    for (int w = 0; w < wave; ++w) wpre += wsum[w];
    int pre = wpre + v - s4;
    if (base + 0 < n) partial[base + 0] = pre + s1;
    if (base + 1 < n) partial[base + 1] = pre + s2;
    if (base + 2 < n) partial[base + 2] = pre + s3;
    if (base + 3 < n) partial[base + 3] = pre + s4;
    if (tid == 255) blockSums[blockIdx.x] = wsum[0] + wsum[1] + wsum[2] + wsum[3];
}

__global__ void scan_sums(int* __restrict__ bs, int nb) {
    int lane = threadIdx.x;                // 64
    int carry = 0;
    for (int b0 = 0; b0 < nb; b0 += 64) {
        int i = b0 + lane;
        int val = (i < nb) ? bs[i] : 0;
        int v = val;
#pragma unroll
        for (int off = 1; off < 64; off <<= 1) {
            int t = __shfl_up(v, off);
            if (lane >= off) v += t;
        }
        if (i < nb) bs[i] = carry + v - val;   // exclusive
        carry += __shfl(v, 63);
    }
}

__global__ void scan_final(const int* __restrict__ counts, const int* __restrict__ partial,
                           const int* __restrict__ bs, int* __restrict__ offsets,
                           int* __restrict__ nxt, int n) {
    int i = blockIdx.x * 256 + threadIdx.x;
    if (i >= n) return;
    int inc = partial[i] + bs[i >> 10];
    offsets[i + 1] = inc;
    nxt[i] = inc - counts[i];
    if (i == 0) offsets[0] = 0;
}

__global__ void scatter_csr(const int* __restrict__ ei, int* __restrict__ nxt,
                            int* __restrict__ csr_src, int E,
                            const int* __restrict__ flag) {
    int e = blockIdx.x * blockDim.x + threadIdx.x;
    if (e >= E) return;
    int is64 = (*flag == 0);
    int s = load_src(ei, e, E, is64);
    int d = load_dst(ei, e, E, is64);
    int pos = atomicAdd(&nxt[d], 1);
    csr_src[pos] = s;
}

// ---- fused q/k/v/s GEMM ----------------------------------------------------
// Wave: 8 rows x 4 matrices. x broadcast via readlane (SGPR path); weight quad
// via one ds_read_b128 per c-step (1 LDS op / 32 FMAs). c-loop split in two
// 32-channel halves so LDS = 32 KiB -> 5 blocks/CU (was 2 at 64 KiB).
__launch_bounds__(256)
__global__ void gemm_qkvs(const float* __restrict__ x,
                          const float* __restrict__ Wq, const float* __restrict__ bq,
                          const float* __restrict__ Wk, const float* __restrict__ bk,
                          const float* __restrict__ Wv, const float* __restrict__ bv,
                          const float* __restrict__ Ws, const float* __restrict__ bs,
                          float* __restrict__ q, float* __restrict__ k,
                          float* __restrict__ v, float* __restrict__ s, int n) {
    __shared__ float Wh[32 * 256];  // 32 KiB: Wh[c][lane][4] for one c-half
    int tid = threadIdx.x;
    int wave = tid >> 6, lane = tid & 63;
    int row0 = blockIdx.x * 32 + wave * 8;

    float xr[8];
#pragma unroll
    for (int j = 0; j < 8; ++j)
        xr[j] = (row0 + j < n) ? x[(size_t)(row0 + j) * D64 + lane] : 0.f;

    float bqv = bq[lane], bkv = bk[lane], bvv = bv[lane], bsv = bs[lane];
    float aq[8], ak[8], av[8], as_[8];
#pragma unroll
    for (int j = 0; j < 8; ++j) { aq[j] = bqv; ak[j] = bkv; av[j] = bvv; as_[j] = bsv; }

    for (int half = 0; half < 2; ++half) {
        int c0 = half * 32;
        // stage this half's weights, interleaved quad per (c, lane)
        for (int i = tid; i < 32 * 64; i += 256) {
            int c = i >> 6, l = i & 63;
            int gi = (c0 + c) * 64 + l;
            float4 wv4;
            wv4.x = Wq[gi]; wv4.y = Wk[gi]; wv4.z = Wv[gi]; wv4.w = Ws[gi];
            *(float4*)&Wh[c * 256 + l * 4] = wv4;
        }
        __syncthreads();
#pragma unroll 4
        for (int cc = 0; cc < 32; ++cc) {
            int c = c0 + cc;
            const float4 w = *(const float4*)&Wh[cc * 256 + lane * 4];
#pragma unroll
            for (int j = 0; j < 8; ++j) {
                float xs = __int_as_float(
                    __builtin_amdgcn_readlane(__float_as_int(xr[j]), c));
                aq[j] += xs * w.x;
                ak[j] += xs * w.y;
                av[j] += xs * w.z;
                as_[j] += xs * w.w;
            }
        }
        __syncthreads();
    }
#pragma unroll
    for (int j = 0; j < 8; ++j) {
        if (row0 + j < n) {
            size_t o = (size_t)(row0 + j) * D64 + lane;
            q[o] = aq[j]; k[o] = ak[j]; v[o] = av[j]; s[o] = as_[j];
        }
    }
}

// ---- fused edge-score + online-softmax aggregation + epilogue --------------
// Wave = 1 node. 8 groups x 8 lanes; group owns one edge/iter (8 in flight),
// lane l8 owns channels [8*l8, 8*l8+8) as 2x float4. Explicit 2-deep pipeline:
// next edge's k/v loads issue before current edge's compute. Online
// (m, den, acc) per group; butterfly-merged over xor 8/16/32 at the end.
// MODE 1: out = silu(t)   MODE 2: out = silu(t + xin)   MODE 3: out = t + 0.1*z
template <int MODE>
__launch_bounds__(256)
__global__ void agg_fused(const float* __restrict__ q, const float* __restrict__ k,
                          const float* __restrict__ v, const int* __restrict__ csr_src,
                          const int* __restrict__ offsets,
                          const float* __restrict__ sbuf, const float* __restrict__ xin,
                          const float* __restrict__ z, float* __restrict__ out, int n) {
    int node = blockIdx.x * 4 + (threadIdx.x >> 6);
    if (node >= n) return;
    int lane = threadIdx.x & 63;
    int grp = lane >> 3, l8 = lane & 7;
    int start = offsets[node], end = offsets[node + 1];
    size_t co = (size_t)node * D64 + l8 * 8;
    float4 ta = *(const float4*)(sbuf + co);       // skip term, ch [8l8, 8l8+4)
    float4 tb = *(const float4*)(sbuf + co + 4);   //            ch [8l8+4, 8l8+8)

    if (end > start) {
        const float4 qa = *(const float4*)(q + co);
        const float4 qb = *(const float4*)(q + co + 4);
        float m = -3.0e38f, den = 0.f;
        float4 aa = make_float4(0.f, 0.f, 0.f, 0.f);
        float4 ab = make_float4(0.f, 0.f, 0.f, 0.f);

        int i = start + grp;
        // pipeline prologue: stage 0 loads
        int idx0 = (i < end) ? i : start;
        int sj0 = csr_src[idx0];
        const float* kp0 = k + (size_t)sj0 * D64 + l8 * 8;
        const float* vp0 = v + (size_t)sj0 * D64 + l8 * 8;
        float4 ka = *(const float4*)kp0, kb = *(const float4*)(kp0 + 4);
        float4 va = *(const float4*)vp0, vb = *(const float4*)(vp0 + 4);

        while (i < end) {
            int inext = i + 8;
            int idx1 = (inext < end) ? inext : start;
            int sj1 = csr_src[idx1];
            const float* kp1 = k + (size_t)sj1 * D64 + l8 * 8;
            const float* vp1 = v + (size_t)sj1 * D64 + l8 * 8;
            float4 ka1 = *(const float4*)kp1, kb1 = *(const float4*)(kp1 + 4);
            float4 va1 = *(const float4*)vp1, vb1 = *(const float4*)(vp1 + 4);

            float p = qa.x * ka.x + qa.y * ka.y + qa.z * ka.z + qa.w * ka.w
                    + qb.x * kb.x + qb.y * kb.y + qb.z * kb.z + qb.w * kb.w;
            p += __shfl_xor(p, 1, 8);
            p += __shfl_xor(p, 2, 8);
            p += __shfl_xor(p, 4, 8);
            p *= 0.125f;                       // 1/sqrt(64)
            float nm = fmaxf(m, p);
            float f  = __expf(m - nm);
            float e  = __expf(p - nm);
            den = den * f + e;
            aa.x = aa.x * f + e * va.x; aa.y = aa.y * f + e * va.y;
            aa.z = aa.z * f + e * va.z; aa.w = aa.w * f + e * va.w;
            ab.x = ab.x * f + e * vb.x; ab.y = ab.y * f + e * vb.y;
            ab.z = ab.z * f + e * vb.z; ab.w = ab.w * f + e * vb.w;
            m = nm;
            ka = ka1; kb = kb1; va = va1; vb = vb1;
            i = inext;
        }
        // butterfly merge of the 8 groups (inactive groups: den=0, exp->0)
        float M = fmaxf(m, __shfl_xor(m, 8));
        M = fmaxf(M, __shfl_xor(M, 16));
        M = fmaxf(M, __shfl_xor(M, 32));
        float f = __expf(m - M);
        float dd = den * f;
        dd += __shfl_xor(dd, 8); dd += __shfl_xor(dd, 16); dd += __shfl_xor(dd, 32);
        aa.x *= f; aa.y *= f; aa.z *= f; aa.w *= f;
        ab.x *= f; ab.y *= f; ab.z *= f; ab.w *= f;
        aa.x += __shfl_xor(aa.x, 8); aa.x += __shfl_xor(aa.x, 16); aa.x += __shfl_xor(aa.x, 32);
        aa.y += __shfl_xor(aa.y, 8); aa.y += __shfl_xor(aa.y, 16); aa.y += __shfl_xor(aa.y, 32);
        aa.z += __shfl_xor(aa.z, 8); aa.z += __shfl_xor(aa.z, 16); aa.z += __shfl_xor(aa.z, 32);
        aa.w += __shfl_xor(aa.w, 8); aa.w += __shfl_xor(aa.w, 16); aa.w += __shfl_xor(aa.w, 32);
        ab.x += __shfl_xor(ab.x, 8); ab.x += __shfl_xor(ab.x, 16); ab.x += __shfl_xor(ab.x, 32);
        ab.y += __shfl_xor(ab.y, 8); ab.y += __shfl_xor(ab.y, 16); ab.y += __shfl_xor(ab.y, 32);
        ab.z += __shfl_xor(ab.z, 8); ab.z += __shfl_xor(ab.z, 16); ab.z += __shfl_xor(ab.z, 32);
        ab.w += __shfl_xor(ab.w, 8); ab.w += __shfl_xor(ab.w, 16); ab.w += __shfl_xor(ab.w, 32);
        float inv = 1.f / dd;
        ta.x += aa.x * inv; ta.y += aa.y * inv; ta.z += aa.z * inv; ta.w += aa.w * inv;
        tb.x += ab.x * inv; tb.y += ab.y * inv; tb.z += ab.z * inv; tb.w += ab.w * inv;
    }
    if (MODE == 1) {
        ta.x = ta.x / (1.f + __expf(-ta.x)); ta.y = ta.y / (1.f + __expf(-ta.y));
        ta.z = ta.z / (1.f + __expf(-ta.z)); ta.w = ta.w / (1.f + __expf(-ta.w));
        tb.x = tb.x / (1.f + __expf(-tb.x)); tb.y = tb.y / (1.f + __expf(-tb.y));
        tb.z = tb.z / (1.f + __expf(-tb.z)); tb.w = tb.w / (1.f + __expf(-tb.w));
    } else if (MODE == 2) {
        const float4 xa = *(const float4*)(xin + co);
        const float4 xb = *(const float4*)(xin + co + 4);
        float u;
        u = ta.x + xa.x; ta.x = u / (1.f + __expf(-u));
        u = ta.y + xa.y; ta.y = u / (1.f + __expf(-u));
        u = ta.z + xa.z; ta.z = u / (1.f + __expf(-u));
        u = ta.w + xa.w; ta.w = u / (1.f + __expf(-u));
        u = tb.x + xb.x; tb.x = u / (1.f + __expf(-u));
        u = tb.y + xb.y; tb.y = u / (1.f + __expf(-u));
        u = tb.z + xb.z; tb.z = u / (1.f + __expf(-u));
        u = tb.w + xb.w; tb.w = u / (1.f + __expf(-u));
    } else {
        const float4 za = *(const float4*)(z + co);
        const float4 zb = *(const float4*)(z + co + 4);
        ta.x += 0.1f * za.x; ta.y += 0.1f * za.y;
        ta.z += 0.1f * za.z; ta.w += 0.1f * za.w;
        tb.x += 0.1f * zb.x; tb.y += 0.1f * zb.y;
        tb.z += 0.1f * zb.z; tb.w += 0.1f * zb.w;
    }
    if (grp == 0) {
        *(float4*)(out + co) = ta;
        *(float4*)(out + co + 4) = tb;
    }
}

// ---------------------------------------------------------------------------
extern "C" void kernel_launch(void* const* d_in, const int* in_sizes, int n_in,
                              void* d_out, int out_size, void* d_ws, size_t ws_size,
                              hipStream_t stream) {
    const float* x = (const float*)d_in[0];
    const int* ei  = (const int*)d_in[1];
    const float* z = (const float*)d_in[2];
    const float* W[3][4];
    const float* B[3][4];
    for (int l = 0; l < 3; ++l)
        for (int m = 0; m < 4; ++m) {
            W[l][m] = (const float*)d_in[3 + l * 8 + m * 2];
            B[l][m] = (const float*)d_in[3 + l * 8 + m * 2 + 1];
        }
    int N = in_sizes[0] / D64;
    int E = in_sizes[1] / 2;
    size_t ND = (size_t)N * D64;

    char* p = (char*)d_ws;
    auto alloc = [&](size_t bytes) {
        char* r = p;
        p += (bytes + 255) & ~(size_t)255;
        return r;
    };
    float* q       = (float*)alloc(ND * 4);
    float* k       = (float*)alloc(ND * 4);
    float* v       = (float*)alloc(ND * 4);
    float* sb      = (float*)alloc(ND * 4);
    float* hA      = (float*)alloc(ND * 4);
    int* csr_src   = (int*)alloc((size_t)E * 4);
    int* offsets   = (int*)alloc((size_t)(N + 1) * 4);
    int* counts    = (int*)alloc((size_t)N * 4);
    int* nxt       = (int*)alloc((size_t)N * 4);
    int* partial   = (int*)alloc((size_t)N * 4);
    int* blockSums = (int*)alloc(4096);
    int* flag      = (int*)alloc(4);
    float* outp    = (float*)d_out;

    hipMemsetAsync(flag, 0, 4, stream);
    hipMemsetAsync(counts, 0, (size_t)N * 4, stream);
    int nchecks = E < 4096 ? E : 4096;
    detect_fmt<<<1, 256, 0, stream>>>(ei, nchecks, flag);
    hist_dst<<<(E + 255) / 256, 256, 0, stream>>>(ei, counts, E, flag);
    int nb = (N + 1023) / 1024;
    scan_blocks<<<nb, 256, 0, stream>>>(counts, partial, blockSums, N);
    scan_sums<<<1, 64, 0, stream>>>(blockSums, nb);
    scan_final<<<(N + 255) / 256, 256, 0, stream>>>(counts, partial, blockSums,
                                                    offsets, nxt, N);
    scatter_csr<<<(E + 255) / 256, 256, 0, stream>>>(ei, nxt, csr_src, E, flag);

    int gemm_grid = (N + 31) / 32;
    int node_grid = (N + 3) / 4;

    // layer 1: x -> hA, silu
    gemm_qkvs<<<gemm_grid, 256, 0, stream>>>(x, W[0][0], B[0][0], W[0][1], B[0][1],
                                             W[0][2], B[0][2], W[0][3], B[0][3],
                                             q, k, v, sb, N);
    agg_fused<1><<<node_grid, 256, 0, stream>>>(q, k, v, csr_src, offsets, sb,
                                                nullptr, nullptr, hA, N);
    // layer 2: hA -> hA (residual + silu)
    gemm_qkvs<<<gemm_grid, 256, 0, stream>>>(hA, W[1][0], B[1][0], W[1][1], B[1][1],
                                             W[1][2], B[1][2], W[1][3], B[1][3],
                                             q, k, v, sb, N);
    agg_fused<2><<<node_grid, 256, 0, stream>>>(q, k, v, csr_src, offsets, sb,
                                                hA, nullptr, hA, N);
    // layer 3: hA -> out, + 0.1*z
    gemm_qkvs<<<gemm_grid, 256, 0, stream>>>(hA, W[2][0], B[2][0], W[2][1], B[2][1],
                                             W[2][2], B[2][2], W[2][3], B[2][3],
                                             q, k, v, sb, N);
    agg_fused<3><<<node_grid, 256, 0, stream>>>(q, k, v, csr_src, offsets, sb,
                                                nullptr, z, outp, N);
}

// Round 6
// 377.847 us; speedup vs baseline: 6.8700x; 1.0473x over previous
//
#include <hip/hip_runtime.h>
#include <math.h>

// ---------------------------------------------------------------------------
// PseqStepV3: 3-layer TransformerConv (heads=1), N=50000, E=800000, D=64.
//   setup: detect edge dtype, build CSR by dst (multi-block scan)
//   per layer: fused q/kv/s GEMM (readlane broadcast, 16 rows/wave,
//              split-c 32KB LDS; k fp32 + v bf16 packed in one 384B row)
//              -> fused online-softmax aggregation (single-row kv gather)
// ---------------------------------------------------------------------------

#define D64 64
#define KVF 96   // floats per kv row: 64 fp32 k + 32 floats (64 bf16) v

__device__ __forceinline__ unsigned short bf16_rne(float f) {
    unsigned int u = __float_as_uint(f);
    u += 0x7FFFu + ((u >> 16) & 1u);
    return (unsigned short)(u >> 16);
}
__device__ __forceinline__ float bf16_to_f(unsigned short h) {
    return __uint_as_float(((unsigned int)h) << 16);
}

// ---- edge_index format detection: int64 rows have zero high words ----------
__global__ void detect_fmt(const int* __restrict__ ei, int nchecks, int* flag) {
    int t = blockIdx.x * blockDim.x + threadIdx.x;
    int acc = 0;
    for (int i = t; i < nchecks; i += blockDim.x * gridDim.x)
        acc |= ei[2 * i + 1];
    if (acc) atomicOr(flag, 1);   // nonzero => plain int32 layout
}

__device__ __forceinline__ int load_src(const int* ei, int e, int E, int is64) {
    return is64 ? ei[2 * e] : ei[e];
}
__device__ __forceinline__ int load_dst(const int* ei, int e, int E, int is64) {
    return is64 ? ei[2 * E + 2 * e] : ei[E + e];
}

// ---- CSR build -------------------------------------------------------------
__global__ void hist_dst(const int* __restrict__ ei, int* __restrict__ counts,
                         int E, const int* __restrict__ flag) {
    int e = blockIdx.x * blockDim.x + threadIdx.x;
    if (e >= E) return;
    int is64 = (*flag == 0);
    atomicAdd(&counts[load_dst(ei, e, E, is64)], 1);
}

__global__ void scan_blocks(const int* __restrict__ counts, int* __restrict__ partial,
                            int* __restrict__ blockSums, int n) {
    int tid = threadIdx.x;                 // 256
    int base = blockIdx.x * 1024 + tid * 4;
    int4 c = make_int4(0, 0, 0, 0);
    if (base + 3 < n) c = *(const int4*)&counts[base];
    else {
        if (base + 0 < n) c.x = counts[base + 0];
        if (base + 1 < n) c.y = counts[base + 1];
        if (base + 2 < n) c.z = counts[base + 2];
        if (base + 3 < n) c.w = counts[base + 3];
    }
    int s1 = c.x, s2 = s1 + c.y, s3 = s2 + c.z, s4 = s3 + c.w;
    int lane = tid & 63, wave = tid >> 6;
    int v = s4;
#pragma unroll
    for (int off = 1; off < 64; off <<= 1) {
        int t = __shfl_up(v, off);
        if (lane >= off) v += t;
    }
    __shared__ int wsum[4];
    if (lane == 63) wsum[wave] = v;
    __syncthreads();
    int wpre = 0;
    for (int w = 0; w < wave; ++w) wpre += wsum[w];
    int pre = wpre + v - s4;
    if (base + 0 < n) partial[base + 0] = pre + s1;
    if (base + 1 < n) partial[base + 1] = pre + s2;
    if (base + 2 < n) partial[base + 2] = pre + s3;
    if (base + 3 < n) partial[base + 3] = pre + s4;
    if (tid == 255) blockSums[blockIdx.x] = wsum[0] + wsum[1] + wsum[2] + wsum[3];
}

__global__ void scan_sums(int* __restrict__ bs, int nb) {
    int lane = threadIdx.x;                // 64
    int carry = 0;
    for (int b0 = 0; b0 < nb; b0 += 64) {
        int i = b0 + lane;
        int val = (i < nb) ? bs[i] : 0;
        int v = val;
#pragma unroll
        for (int off = 1; off < 64; off <<= 1) {
            int t = __shfl_up(v, off);
            if (lane >= off) v += t;
        }
        if (i < nb) bs[i] = carry + v - val;   // exclusive
        carry += __shfl(v, 63);
    }
}

__global__ void scan_final(const int* __restrict__ counts, const int* __restrict__ partial,
                           const int* __restrict__ bs, int* __restrict__ offsets,
                           int* __restrict__ nxt, int n) {
    int i = blockIdx.x * 256 + threadIdx.x;
    if (i >= n) return;
    int inc = partial[i] + bs[i >> 10];
    offsets[i + 1] = inc;
    nxt[i] = inc - counts[i];
    if (i == 0) offsets[0] = 0;
}

__global__ void scatter_csr(const int* __restrict__ ei, int* __restrict__ nxt,
                            int* __restrict__ csr_src, int E,
                            const int* __restrict__ flag) {
    int e = blockIdx.x * blockDim.x + threadIdx.x;
    if (e >= E) return;
    int is64 = (*flag == 0);
    int s = load_src(ei, e, E, is64);
    int d = load_dst(ei, e, E, is64);
    int pos = atomicAdd(&nxt[d], 1);
    csr_src[pos] = s;
}

// ---- fused q/kv/s GEMM -----------------------------------------------------
// Wave: 16 rows x 4 matrices. x broadcast via readlane (SGPR path); weight
// quad via one ds_read_b128 per c-step (1 LDS op / 64 FMAs). c-loop split in
// two 32-channel halves so LDS = 32 KiB. Outputs: q fp32, s fp32, and a packed
// kv row per node: 64 fp32 k + 64 bf16 v = 384 B contiguous (one-gather agg).
__launch_bounds__(256)
__global__ void gemm_qkvs(const float* __restrict__ x,
                          const float* __restrict__ Wq, const float* __restrict__ bq,
                          const float* __restrict__ Wk, const float* __restrict__ bk,
                          const float* __restrict__ Wv, const float* __restrict__ bv,
                          const float* __restrict__ Ws, const float* __restrict__ bs,
                          float* __restrict__ q, float* __restrict__ kv,
                          float* __restrict__ s, int n) {
    __shared__ float Wh[32 * 256];  // 32 KiB: Wh[c][lane][4] for one c-half
    int tid = threadIdx.x;
    int wave = tid >> 6, lane = tid & 63;
    int row0 = blockIdx.x * 64 + wave * 16;

    float xr[16];
#pragma unroll
    for (int j = 0; j < 16; ++j)
        xr[j] = (row0 + j < n) ? x[(size_t)(row0 + j) * D64 + lane] : 0.f;

    float bqv = bq[lane], bkv = bk[lane], bvv = bv[lane], bsv = bs[lane];
    float aq[16], ak[16], av[16], as_[16];
#pragma unroll
    for (int j = 0; j < 16; ++j) { aq[j] = bqv; ak[j] = bkv; av[j] = bvv; as_[j] = bsv; }

    for (int half = 0; half < 2; ++half) {
        int c0 = half * 32;
        for (int i = tid; i < 32 * 64; i += 256) {
            int c = i >> 6, l = i & 63;
            int gi = (c0 + c) * 64 + l;
            float4 wv4;
            wv4.x = Wq[gi]; wv4.y = Wk[gi]; wv4.z = Wv[gi]; wv4.w = Ws[gi];
            *(float4*)&Wh[c * 256 + l * 4] = wv4;
        }
        __syncthreads();
#pragma unroll 4
        for (int cc = 0; cc < 32; ++cc) {
            int c = c0 + cc;
            const float4 w = *(const float4*)&Wh[cc * 256 + lane * 4];
#pragma unroll
            for (int j = 0; j < 16; ++j) {
                float xs = __int_as_float(
                    __builtin_amdgcn_readlane(__float_as_int(xr[j]), c));
                aq[j] += xs * w.x;
                ak[j] += xs * w.y;
                av[j] += xs * w.z;
                as_[j] += xs * w.w;
            }
        }
        __syncthreads();
    }
#pragma unroll
    for (int j = 0; j < 16; ++j) {
        if (row0 + j < n) {
            size_t o = (size_t)(row0 + j) * D64 + lane;
            q[o] = aq[j]; s[o] = as_[j];
            size_t rb = (size_t)(row0 + j) * KVF;
            kv[rb + lane] = ak[j];                         // k fp32, 256B row
            unsigned short* vp = (unsigned short*)(kv + rb + 64);
            vp[lane] = bf16_rne(av[j]);                    // v bf16, 128B row
        }
    }
}

// ---- fused edge-score + online-softmax aggregation + epilogue --------------
// Wave = 1 node. 8 groups x 8 lanes; group owns one edge/iter, lane l8 owns
// channels [8*l8, 8*l8+8). Per edge one contiguous 384B kv-row gather:
// 2x float4 k (fp32) + 1x float4 = 8x bf16 v. 2-deep load pipeline. Online
// (m, den, acc) per group; butterfly-merged over xor 8/16/32.
// MODE 1: out = silu(t)   MODE 2: out = silu(t + xin)   MODE 3: out = t + 0.1*z
template <int MODE>
__launch_bounds__(256)
__global__ void agg_fused(const float* __restrict__ q, const float* __restrict__ kv,
                          const int* __restrict__ csr_src,
                          const int* __restrict__ offsets,
                          const float* __restrict__ sbuf, const float* __restrict__ xin,
                          const float* __restrict__ z, float* __restrict__ out, int n) {
    int node = blockIdx.x * 4 + (threadIdx.x >> 6);
    if (node >= n) return;
    int lane = threadIdx.x & 63;
    int grp = lane >> 3, l8 = lane & 7;
    int start = offsets[node], end = offsets[node + 1];
    size_t co = (size_t)node * D64 + l8 * 8;
    float4 ta = *(const float4*)(sbuf + co);       // skip term, ch [8l8, 8l8+4)
    float4 tb = *(const float4*)(sbuf + co + 4);   //            ch [8l8+4, 8l8+8)

    if (end > start) {
        const float4 qa = *(const float4*)(q + co);
        const float4 qb = *(const float4*)(q + co + 4);
        float m = -3.0e38f, den = 0.f;
        float4 aa = make_float4(0.f, 0.f, 0.f, 0.f);
        float4 ab = make_float4(0.f, 0.f, 0.f, 0.f);

        int i = start + grp;
        int idx0 = (i < end) ? i : start;
        int sj0 = csr_src[idx0];
        const float* kp0 = kv + (size_t)sj0 * KVF;
        float4 ka = *(const float4*)(kp0 + l8 * 8);
        float4 kb = *(const float4*)(kp0 + l8 * 8 + 4);
        float4 vr = *(const float4*)(kp0 + 64 + l8 * 4);   // 8 bf16

        while (i < end) {
            int inext = i + 8;
            int idx1 = (inext < end) ? inext : start;
            int sj1 = csr_src[idx1];
            const float* kp1 = kv + (size_t)sj1 * KVF;
            float4 ka1 = *(const float4*)(kp1 + l8 * 8);
            float4 kb1 = *(const float4*)(kp1 + l8 * 8 + 4);
            float4 vr1 = *(const float4*)(kp1 + 64 + l8 * 4);

            float p = qa.x * ka.x + qa.y * ka.y + qa.z * ka.z + qa.w * ka.w
                    + qb.x * kb.x + qb.y * kb.y + qb.z * kb.z + qb.w * kb.w;
            p += __shfl_xor(p, 1, 8);
            p += __shfl_xor(p, 2, 8);
            p += __shfl_xor(p, 4, 8);
            p *= 0.125f;                       // 1/sqrt(64)
            float nm = fmaxf(m, p);
            float f  = __expf(m - nm);
            float e  = __expf(p - nm);
            den = den * f + e;
            // unpack 8 bf16 v channels from vr
            unsigned int u0 = __float_as_uint(vr.x), u1 = __float_as_uint(vr.y);
            unsigned int u2 = __float_as_uint(vr.z), u3 = __float_as_uint(vr.w);
            float v0 = __uint_as_float(u0 << 16), v1 = __uint_as_float(u0 & 0xFFFF0000u);
            float v2 = __uint_as_float(u1 << 16), v3 = __uint_as_float(u1 & 0xFFFF0000u);
            float v4 = __uint_as_float(u2 << 16), v5 = __uint_as_float(u2 & 0xFFFF0000u);
            float v6 = __uint_as_float(u3 << 16), v7 = __uint_as_float(u3 & 0xFFFF0000u);
            aa.x = aa.x * f + e * v0; aa.y = aa.y * f + e * v1;
            aa.z = aa.z * f + e * v2; aa.w = aa.w * f + e * v3;
            ab.x = ab.x * f + e * v4; ab.y = ab.y * f + e * v5;
            ab.z = ab.z * f + e * v6; ab.w = ab.w * f + e * v7;
            m = nm;
            ka = ka1; kb = kb1; vr = vr1;
            i = inext;
        }
        // butterfly merge of the 8 groups (inactive groups: den=0, exp->0)
        float M = fmaxf(m, __shfl_xor(m, 8));
        M = fmaxf(M, __shfl_xor(M, 16));
        M = fmaxf(M, __shfl_xor(M, 32));
        float f = __expf(m - M);
        float dd = den * f;
        dd += __shfl_xor(dd, 8); dd += __shfl_xor(dd, 16); dd += __shfl_xor(dd, 32);
        aa.x *= f; aa.y *= f; aa.z *= f; aa.w *= f;
        ab.x *= f; ab.y *= f; ab.z *= f; ab.w *= f;
        aa.x += __shfl_xor(aa.x, 8); aa.x += __shfl_xor(aa.x, 16); aa.x += __shfl_xor(aa.x, 32);
        aa.y += __shfl_xor(aa.y, 8); aa.y += __shfl_xor(aa.y, 16); aa.y += __shfl_xor(aa.y, 32);
        aa.z += __shfl_xor(aa.z, 8); aa.z += __shfl_xor(aa.z, 16); aa.z += __shfl_xor(aa.z, 32);
        aa.w += __shfl_xor(aa.w, 8); aa.w += __shfl_xor(aa.w, 16); aa.w += __shfl_xor(aa.w, 32);
        ab.x += __shfl_xor(ab.x, 8); ab.x += __shfl_xor(ab.x, 16); ab.x += __shfl_xor(ab.x, 32);
        ab.y += __shfl_xor(ab.y, 8); ab.y += __shfl_xor(ab.y, 16); ab.y += __shfl_xor(ab.y, 32);
        ab.z += __shfl_xor(ab.z, 8); ab.z += __shfl_xor(ab.z, 16); ab.z += __shfl_xor(ab.z, 32);
        ab.w += __shfl_xor(ab.w, 8); ab.w += __shfl_xor(ab.w, 16); ab.w += __shfl_xor(ab.w, 32);
        float inv = 1.f / dd;
        ta.x += aa.x * inv; ta.y += aa.y * inv; ta.z += aa.z * inv; ta.w += aa.w * inv;
        tb.x += ab.x * inv; tb.y += ab.y * inv; tb.z += ab.z * inv; tb.w += ab.w * inv;
    }
    if (MODE == 1) {
        ta.x = ta.x / (1.f + __expf(-ta.x)); ta.y = ta.y / (1.f + __expf(-ta.y));
        ta.z = ta.z / (1.f + __expf(-ta.z)); ta.w = ta.w / (1.f + __expf(-ta.w));
        tb.x = tb.x / (1.f + __expf(-tb.x)); tb.y = tb.y / (1.f + __expf(-tb.y));
        tb.z = tb.z / (1.f + __expf(-tb.z)); tb.w = tb.w / (1.f + __expf(-tb.w));
    } else if (MODE == 2) {
        const float4 xa = *(const float4*)(xin + co);
        const float4 xb = *(const float4*)(xin + co + 4);
        float u;
        u = ta.x + xa.x; ta.x = u / (1.f + __expf(-u));
        u = ta.y + xa.y; ta.y = u / (1.f + __expf(-u));
        u = ta.z + xa.z; ta.z = u / (1.f + __expf(-u));
        u = ta.w + xa.w; ta.w = u / (1.f + __expf(-u));
        u = tb.x + xb.x; tb.x = u / (1.f + __expf(-u));
        u = tb.y + xb.y; tb.y = u / (1.f + __expf(-u));
        u = tb.z + xb.z; tb.z = u / (1.f + __expf(-u));
        u = tb.w + xb.w; tb.w = u / (1.f + __expf(-u));
    } else {
        const float4 za = *(const float4*)(z + co);
        const float4 zb = *(const float4*)(z + co + 4);
        ta.x += 0.1f * za.x; ta.y += 0.1f * za.y;
        ta.z += 0.1f * za.z; ta.w += 0.1f * za.w;
        tb.x += 0.1f * zb.x; tb.y += 0.1f * zb.y;
        tb.z += 0.1f * zb.z; tb.w += 0.1f * zb.w;
    }
    if (grp == 0) {
        *(float4*)(out + co) = ta;
        *(float4*)(out + co + 4) = tb;
    }
}

// ---------------------------------------------------------------------------
extern "C" void kernel_launch(void* const* d_in, const int* in_sizes, int n_in,
                              void* d_out, int out_size, void* d_ws, size_t ws_size,
                              hipStream_t stream) {
    const float* x = (const float*)d_in[0];
    const int* ei  = (const int*)d_in[1];
    const float* z = (const float*)d_in[2];
    const float* W[3][4];
    const float* B[3][4];
    for (int l = 0; l < 3; ++l)
        for (int m = 0; m < 4; ++m) {
            W[l][m] = (const float*)d_in[3 + l * 8 + m * 2];
            B[l][m] = (const float*)d_in[3 + l * 8 + m * 2 + 1];
        }
    int N = in_sizes[0] / D64;
    int E = in_sizes[1] / 2;
    size_t ND = (size_t)N * D64;

    char* p = (char*)d_ws;
    auto alloc = [&](size_t bytes) {
        char* r = p;
        p += (bytes + 255) & ~(size_t)255;
        return r;
    };
    float* q       = (float*)alloc(ND * 4);
    float* kv      = (float*)alloc((size_t)N * KVF * 4);
    float* sb      = (float*)alloc(ND * 4);
    float* hA      = (float*)alloc(ND * 4);
    int* csr_src   = (int*)alloc((size_t)E * 4);
    int* offsets   = (int*)alloc((size_t)(N + 1) * 4);
    int* counts    = (int*)alloc((size_t)N * 4);
    int* nxt       = (int*)alloc((size_t)N * 4);
    int* partial   = (int*)alloc((size_t)N * 4);
    int* blockSums = (int*)alloc(4096);
    int* flag      = (int*)alloc(4);
    float* outp    = (float*)d_out;

    hipMemsetAsync(flag, 0, 4, stream);
    hipMemsetAsync(counts, 0, (size_t)N * 4, stream);
    int nchecks = E < 4096 ? E : 4096;
    detect_fmt<<<1, 256, 0, stream>>>(ei, nchecks, flag);
    hist_dst<<<(E + 255) / 256, 256, 0, stream>>>(ei, counts, E, flag);
    int nb = (N + 1023) / 1024;
    scan_blocks<<<nb, 256, 0, stream>>>(counts, partial, blockSums, N);
    scan_sums<<<1, 64, 0, stream>>>(blockSums, nb);
    scan_final<<<(N + 255) / 256, 256, 0, stream>>>(counts, partial, blockSums,
                                                    offsets, nxt, N);
    scatter_csr<<<(E + 255) / 256, 256, 0, stream>>>(ei, nxt, csr_src, E, flag);

    int gemm_grid = (N + 63) / 64;
    int node_grid = (N + 3) / 4;

    // layer 1: x -> hA, silu
    gemm_qkvs<<<gemm_grid, 256, 0, stream>>>(x, W[0][0], B[0][0], W[0][1], B[0][1],
                                             W[0][2], B[0][2], W[0][3], B[0][3],
                                             q, kv, sb, N);
    agg_fused<1><<<node_grid, 256, 0, stream>>>(q, kv, csr_src, offsets, sb,
                                                nullptr, nullptr, hA, N);
    // layer 2: hA -> hA (residual + silu)
    gemm_qkvs<<<gemm_grid, 256, 0, stream>>>(hA, W[1][0], B[1][0], W[1][1], B[1][1],
                                             W[1][2], B[1][2], W[1][3], B[1][3],
                                             q, kv, sb, N);
    agg_fused<2><<<node_grid, 256, 0, stream>>>(q, kv, csr_src, offsets, sb,
                                                hA, nullptr, hA, N);
    // layer 3: hA -> out, + 0.1*z
    gemm_qkvs<<<gemm_grid, 256, 0, stream>>>(hA, W[2][0], B[2][0], W[2][1], B[2][1],
                                             W[2][2], B[2][2], W[2][3], B[2][3],
                                             q, kv, sb, N);
    agg_fused<3><<<node_grid, 256, 0, stream>>>(q, kv, csr_src, offsets, sb,
                                                nullptr, z, outp, N);
}